// Round 7
// baseline (735.119 us; speedup 1.0000x reference)
//
#include <hip/hip_runtime.h>
#include <hip/hip_bf16.h>
#include <math.h>

// Problem constants
#define E_   131072
#define N_   600
#define NB_  2
#define NQ_  300
#define NK_  1024
#define NH_  8

typedef __hip_bfloat16 bf16;
typedef __bf16 bh8 __attribute__((ext_vector_type(8)));
typedef float  fx4 __attribute__((ext_vector_type(4)));

static __device__ __forceinline__ float b2f(bf16 x){ return __bfloat162float(x); }
static __device__ __forceinline__ float bfbits2f(unsigned short u){
  return __uint_as_float((unsigned)u << 16);
}
static __device__ __forceinline__ unsigned short bfu(float x){
  return __bfloat16_as_ushort(__float2bfloat16(x));
}
static __device__ __forceinline__ unsigned pack2(float x, float y){
  return (unsigned)bfu(x) | ((unsigned)bfu(y) << 16);
}
// dual-dtype scalar load: isf32 ? f32[i] : bf16[i]
static __device__ __forceinline__ float ldf(const void* p, size_t i, bool isf32){
  return isf32 ? ((const float*)p)[i] : b2f(((const bf16*)p)[i]);
}

// per-block dtype sniff: wave 0 examines first 64 ushorts of nodes (same
// heuristic as the old k_init), broadcasts via LDS. Removes the k_init
// dispatch and all cross-kernel dflag dependencies.
static __device__ __forceinline__ bool get_isf32(const void* nodes, int t, int* sh){
  if (t < 64){
    const unsigned short* h = (const unsigned short*)nodes;
    int e = (h[t] >> 7) & 0xFF;
    unsigned long long b = __ballot(e < 100 || e > 150);
    if (t == 0) *sh = (__popcll(b) > 8) ? 1 : 0;
  }
  __syncthreads();
  return *sh != 0;
}

// ---- converted-weight table offsets (elements); seg 30 = We ----
constexpr int WOFF[32] = {
  0,256,512,768,1024,1280,
  1536,67072,67328,132864,
  133120,133376,
  133632,264704,
  264960,330496,330752,396288,
  396544,527616,
  528128,528640,528896,530944,
  530952,596488,
  596744,858888,859912,1122056,
  1122312,
  1187848};
#define NWSEG 31
#define WTOT  1187848
struct SrcTab { const void* p[NWSEG]; };
struct TrTabP { const void* p[8]; int4 d[8]; };  // y=K, z=N, w=dstOff(Wbt)

// block-wide LayerNorm stats over 256 values (one per thread), 4 waves
static __device__ __forceinline__ void ln_stats(float v, int t, float* r1, float* r2,
                                                float& mu, float& rstd){
  float s1 = v, s2 = v*v;
  #pragma unroll
  for (int o = 32; o; o >>= 1){ s1 += __shfl_down(s1, o); s2 += __shfl_down(s2, o); }
  if ((t & 63) == 0){ r1[t>>6] = s1; r2[t>>6] = s2; }
  __syncthreads();
  float t1 = r1[0]+r1[1]+r1[2]+r1[3];
  float t2 = r2[0]+r2[1]+r2[2]+r2[3];
  mu = t1 * (1.f/256.f);
  float var = t2 * (1.f/256.f) - mu*mu;
  rstd = rsqrtf(var + 1e-5f);
  __syncthreads();
}

// ======== MEGA PREP: cvt | tr | ln1 | denom-zero in ONE dispatch ========
#define PB_CVT 4641
#define PB_TR  2048
#define PB_LN1 600
#define PB_DEN 19
#define PB_TOTAL (PB_CVT + PB_TR + PB_LN1 + PB_DEN)

__global__ __launch_bounds__(256) void k_prep(
    SrcTab tab, TrTabP trp, float* __restrict__ wall, bf16* __restrict__ wbt,
    const void* __restrict__ nodes, bf16* __restrict__ x1, float* __restrict__ denom)
{
  __shared__ float tile[64][65];
  __shared__ float r1[4], r2[4];
  __shared__ int dsh;
  int t = threadIdx.x;
  int b = blockIdx.x;
  bool isf32 = get_isf32(nodes, t, &dsh);
  if (b < PB_CVT){
    int i = b*256 + t;
    if (i < WTOT){
      int seg = 0;
      while (seg < NWSEG-1 && i >= WOFF[seg+1]) seg++;
      wall[i] = ldf(tab.p[seg], (size_t)(i - WOFF[seg]), isf32);
    }
  } else if (b < PB_CVT + PB_TR){
    // 64x64 transpose tiles, reading RAW sources via ldf (no Wall dep)
    int lb = b - PB_CVT;
    int bz = lb >> 8, by = (lb >> 4) & 15, bx = lb & 15;
    int4 d = trp.d[bz];
    int K = d.y, Nn = d.z;
    int k0 = bx*64, n0 = by*64;
    if (k0 < K && n0 < Nn){
      const void* src = trp.p[bz];
      bf16* dst = wbt + d.w;
      int rr = t >> 6, cc = t & 63;
      #pragma unroll
      for (int p = 0; p < 16; p++){
        int row = p*4 + rr;
        tile[row][cc] = ldf(src, (size_t)(k0 + row)*Nn + n0 + cc, isf32);
      }
      __syncthreads();
      #pragma unroll
      for (int p = 0; p < 16; p++){
        int row = p*4 + rr;
        dst[(size_t)(n0 + row)*K + k0 + cc] = __float2bfloat16(tile[cc][row]);
      }
    }
  } else if (b < PB_CVT + PB_TR + PB_LN1){
    int n = b - (PB_CVT + PB_TR);
    float v = ldf(nodes, (size_t)n*256 + t, isf32);
    float mu, rstd;
    ln_stats(v, t, r1, r2, mu, rstd);
    float g  = ldf(tab.p[0], t, isf32);   // ln1_g = d_in[6]
    float bb = ldf(tab.p[1], t, isf32);   // ln1_b = d_in[7]
    x1[n*256 + t] = __float2bfloat16((v - mu) * rstd * g + bb);
  } else {
    int i = (b - (PB_CVT + PB_TR + PB_LN1))*256 + t;
    if (i < N_*NH_) denom[i] = 0.f;
  }
}

// ======== count + scan fused: one block counts via LDS atomics, scans ========
__global__ __launch_bounds__(1024) void k_scan(const int* __restrict__ ei,
                                               int* offs, int* cursor){
  __shared__ int s[1024];
  int t = threadIdx.x;
  s[t] = 0;
  __syncthreads();
  for (int i = t; i < E_; i += 1024)
    atomicAdd(&s[ei[i]], 1);
  __syncthreads();
  for (int o = 1; o < 1024; o <<= 1){
    int v = 0;
    if (t >= o) v = s[t - o];
    __syncthreads();
    if (t >= o) s[t] += v;
    __syncthreads();
  }
  if (t < N_){ int excl = (t == 0) ? 0 : s[t-1]; offs[t] = excl; cursor[t] = excl; }
  if (t == N_-1) offs[N_] = s[N_-1];
}

// ======== generic MFMA GEMM body (BK=64), shared-memory passed in ========
static __device__ void gemm_body(
    const void* __restrict__ A, bool f32src, int K, int M,
    const bf16* __restrict__ BT, int mode,
    void* __restrict__ D, int ldd,
    const float* __restrict__ bias, const float* __restrict__ add,
    float* __restrict__ aux,
    int bx, int by, int t, bf16* As, bf16* Bs)
{
  int m0 = bx * 128;
  int n0 = by * 128;
  int wave = t >> 6, lane = t & 63;
  int wr = (wave >> 1) * 64, wc = (wave & 1) * 64;
  int lm = lane & 15, lq = lane >> 4;
  int srow = t >> 2;
  int scol = (t & 3) * 16;
  size_t rA0 = (size_t)(m0 + srow) * K;
  size_t rA1 = (size_t)(m0 + 64 + srow) * K;
  size_t rB0 = (size_t)(n0 + srow) * K;
  size_t rB1 = (size_t)(n0 + 64 + srow) * K;
  fx4 acc[4][4] = {};
  for (int kk = 0; kk < K; kk += 64){
    uint4 a00, a01, a10, a11, b00, b01, b10, b11;
    if (f32src){
      const float* p0 = (const float*)A + rA0 + kk + scol;
      const float* p1 = (const float*)A + rA1 + kk + scol;
      float4 x0 = *(const float4*)p0,      x1v = *(const float4*)(p0 + 4);
      float4 x2 = *(const float4*)(p0 + 8), x3 = *(const float4*)(p0 + 12);
      float4 y0 = *(const float4*)p1,      y1v = *(const float4*)(p1 + 4);
      float4 y2 = *(const float4*)(p1 + 8), y3 = *(const float4*)(p1 + 12);
      a00.x = pack2(x0.x,x0.y); a00.y = pack2(x0.z,x0.w);
      a00.z = pack2(x1v.x,x1v.y); a00.w = pack2(x1v.z,x1v.w);
      a01.x = pack2(x2.x,x2.y); a01.y = pack2(x2.z,x2.w);
      a01.z = pack2(x3.x,x3.y); a01.w = pack2(x3.z,x3.w);
      a10.x = pack2(y0.x,y0.y); a10.y = pack2(y0.z,y0.w);
      a10.z = pack2(y1v.x,y1v.y); a10.w = pack2(y1v.z,y1v.w);
      a11.x = pack2(y2.x,y2.y); a11.y = pack2(y2.z,y2.w);
      a11.z = pack2(y3.x,y3.y); a11.w = pack2(y3.z,y3.w);
    } else {
      const bf16* p0 = (const bf16*)A + rA0 + kk + scol;
      const bf16* p1 = (const bf16*)A + rA1 + kk + scol;
      a00 = *(const uint4*)p0;       a01 = *(const uint4*)(p0 + 8);
      a10 = *(const uint4*)p1;       a11 = *(const uint4*)(p1 + 8);
    }
    b00 = *(const uint4*)(BT + rB0 + kk + scol);
    b01 = *(const uint4*)(BT + rB0 + kk + scol + 8);
    b10 = *(const uint4*)(BT + rB1 + kk + scol);
    b11 = *(const uint4*)(BT + rB1 + kk + scol + 8);
    __syncthreads();
    *(uint4*)(As + srow*72 + scol)          = a00;
    *(uint4*)(As + srow*72 + scol + 8)      = a01;
    *(uint4*)(As + (64+srow)*72 + scol)     = a10;
    *(uint4*)(As + (64+srow)*72 + scol + 8) = a11;
    *(uint4*)(Bs + srow*72 + scol)          = b00;
    *(uint4*)(Bs + srow*72 + scol + 8)      = b01;
    *(uint4*)(Bs + (64+srow)*72 + scol)     = b10;
    *(uint4*)(Bs + (64+srow)*72 + scol + 8) = b11;
    __syncthreads();
    #pragma unroll
    for (int ks = 0; ks < 2; ks++){
      bh8 af[4], bfr[4];
      #pragma unroll
      for (int mt = 0; mt < 4; mt++)
        af[mt] = *reinterpret_cast<const bh8*>(As + (wr + mt*16 + lm)*72 + ks*32 + lq*8);
      #pragma unroll
      for (int nt = 0; nt < 4; nt++)
        bfr[nt] = *reinterpret_cast<const bh8*>(Bs + (wc + nt*16 + lm)*72 + ks*32 + lq*8);
      #pragma unroll
      for (int mt = 0; mt < 4; mt++)
        #pragma unroll
        for (int nt = 0; nt < 4; nt++)
          acc[mt][nt] = __builtin_amdgcn_mfma_f32_16x16x32_bf16(af[mt], bfr[nt], acc[mt][nt], 0, 0, 0);
    }
  }
  #pragma unroll
  for (int mt = 0; mt < 4; mt++)
    #pragma unroll
    for (int nt = 0; nt < 4; nt++)
      #pragma unroll
      for (int r = 0; r < 4; r++){
        int row = m0 + wr + mt*16 + lq*4 + r;
        int col = n0 + wc + nt*16 + lm;
        if (row >= M) continue;
        float v = acc[mt][nt][r];
        if (mode == 0){
          if (bias) v += bias[col];
          ((float*)D)[(size_t)row*ldd + col] = v;
        } else if (mode == 1){
          v += bias[col];
          if (col < 256){
            ((float*)D)[(size_t)row*256 + col] = v;
          } else {
            int b = row >> 10, ki = row & 1023;
            int hh = (col - 256) >> 5, dd = (col - 256) & 31;
            aux[(((size_t)b*NH_ + hh)*32 + dd)*NK_ + ki] = v;
          }
        } else if (mode == 2){
          v += bias[col] + add[(size_t)row*ldd + col];
          ((float*)D)[(size_t)row*ldd + col] = v;
        } else {
          v += bias[col];
          float g = 0.5f*v*(1.f + erff(v*0.70710678118654752f));
          ((bf16*)D)[(size_t)row*ldd + col] = __float2bfloat16(g);
        }
      }
}

// standalone wrapper (Wco / Wf1 / Wf2: always bf16 A)
__global__ __launch_bounds__(256) void k_gemm(
    const void* __restrict__ A, int K, int M, const bf16* __restrict__ BT, int mode,
    void* __restrict__ D, int ldd,
    const float* __restrict__ bias, const float* __restrict__ add,
    float* __restrict__ aux)
{
  __shared__ __align__(16) bf16 As[128*72];
  __shared__ __align__(16) bf16 Bs[128*72];
  gemm_body(A, false, K, M, BT, mode, D, ldd, bias, add, aux,
            blockIdx.x, blockIdx.y, threadIdx.x, As, Bs);
}

// ---- cpb body (device fn; shared decls local) ----
static __device__ void cpb_body(
    const void* __restrict__ rel, bool isf32,
    const float* __restrict__ Wc1, const float* __restrict__ bc1,
    const float* __restrict__ Wc2, const float* __restrict__ bc2,
    bf16* __restrict__ bias, int cb, int t)
{
  __shared__ float w0[256], w1[256], bb[256], w2[256*8], b2s[8];
  w0[t] = Wc1[t]; w1[t] = Wc1[256 + t]; bb[t] = bc1[t];
  for (int i = t; i < 2048; i += 256) w2[i] = Wc2[i];
  if (t < 8) b2s[t] = bc2[t];
  __syncthreads();
  size_t pos = (size_t)cb*256 + t;
  float c0, c1;
  if (isf32){
    float2 v = ((const float2*)rel)[pos];
    c0 = v.x; c1 = v.y;
  } else {
    unsigned v = ((const unsigned*)rel)[pos];
    c0 = bfbits2f((unsigned short)(v & 0xffff));
    c1 = bfbits2f((unsigned short)(v >> 16));
  }
  float acc[8] = {};
  for (int j = 0; j < 256; j++){
    float hj = fmaf(c0, w0[j], fmaf(c1, w1[j], bb[j]));
    hj = fmaxf(hj, 0.f);
    #pragma unroll
    for (int h = 0; h < 8; h++) acc[h] = fmaf(hj, w2[j*8 + h], acc[h]);
  }
  int k = (int)(pos & 1023);
  size_t qq = pos >> 10;
  size_t b = qq / NQ_, q = qq % NQ_;
  bf16* dst = bias + ((b*NH_)*NQ_ + q)*NK_;
  #pragma unroll
  for (int h = 0; h < 8; h++)
    dst[(size_t)h*NQ_*NK_ + k] = __float2bfloat16(acc[h] + b2s[h]);
}

// ======== BATCHED: Pall-gemm | kv-gemm | cpb | scatter in ONE dispatch ========
#define BB_PALL 30
#define BB_KV   64
#define BB_CPB  2400
#define BB_SCAT 512
#define BB_TOTAL (BB_PALL + BB_KV + BB_CPB + BB_SCAT)

__global__ __launch_bounds__(256) void k_batch(
    const bf16* __restrict__ x1, const bf16* __restrict__ WnpT, float* __restrict__ Pall,
    const void* __restrict__ images, const bf16* __restrict__ WkvT,
    float* __restrict__ kbuf, float* __restrict__ vT, const float* __restrict__ bkv,
    const void* __restrict__ rel,
    const float* __restrict__ Wc1, const float* __restrict__ bc1,
    const float* __restrict__ Wc2, const float* __restrict__ bc2, bf16* __restrict__ bias,
    const int* __restrict__ ei, int* __restrict__ cursor, int* __restrict__ eorder,
    const void* __restrict__ nodes)
{
  __shared__ __align__(16) bf16 As[128*72];
  __shared__ __align__(16) bf16 Bs[128*72];
  __shared__ int dsh;
  int t = threadIdx.x, b = blockIdx.x;
  bool isf32 = get_isf32(nodes, t, &dsh);
  if (b < BB_PALL){
    gemm_body(x1, false, 256, N_, WnpT, 0, Pall, 768, nullptr, nullptr, nullptr,
              b % 5, b / 5, t, As, Bs);
  } else if (b < BB_PALL + BB_KV){
    int bb = b - BB_PALL;
    gemm_body(images, isf32, 256, NB_*NK_, WkvT, 1, kbuf, 256, bkv, nullptr, vT,
              bb & 15, bb >> 4, t, As, Bs);
  } else if (b < BB_PALL + BB_KV + BB_CPB){
    cpb_body(rel, isf32, Wc1, bc1, Wc2, bc2, bias, b - (BB_PALL + BB_KV), t);
  } else {
    int e = (b - (BB_PALL + BB_KV + BB_CPB))*256 + t;
    int pos = atomicAdd(&cursor[ei[e]], 1);
    eorder[pos] = e;
  }
}

// ---- He GEMM (dual-dtype A), bf16 out. BK=64, per-block dtype sniff ----
__global__ __launch_bounds__(256) void k_gemm_dual(
    const void* __restrict__ A, int m_base, const void* __restrict__ nodes,
    const bf16* __restrict__ BT, bf16* __restrict__ C)
{
  __shared__ __align__(16) bf16 As[128*72];
  __shared__ __align__(16) bf16 Bs[128*72];
  __shared__ int dsh;
  int t = threadIdx.x;
  bool isf32 = get_isf32(nodes, t, &dsh);
  int m0 = blockIdx.x * 128;
  int n0 = blockIdx.y * 128;
  int wave = t >> 6, lane = t & 63;
  int wr = (wave >> 1) * 64, wc = (wave & 1) * 64;
  int lm = lane & 15, lq = lane >> 4;
  int srow = t >> 2;
  int scol = (t & 3) * 16;
  size_t r0  = (size_t)(m_base + m0 + srow) * 256;
  size_t r1  = (size_t)(m_base + m0 + 64 + srow) * 256;
  size_t rB0 = (size_t)(n0 + srow) * 256;
  size_t rB1 = (size_t)(n0 + 64 + srow) * 256;
  fx4 acc[4][4] = {};
  for (int kk = 0; kk < 256; kk += 64){
    uint4 a00, a01, a10, a11, b00, b01, b10, b11;
    if (isf32){
      const float* p0 = (const float*)A + r0 + kk + scol;
      const float* p1 = (const float*)A + r1 + kk + scol;
      float4 x0 = *(const float4*)p0,      x1v = *(const float4*)(p0 + 4);
      float4 x2 = *(const float4*)(p0 + 8), x3 = *(const float4*)(p0 + 12);
      float4 y0 = *(const float4*)p1,      y1v = *(const float4*)(p1 + 4);
      float4 y2 = *(const float4*)(p1 + 8), y3 = *(const float4*)(p1 + 12);
      a00.x = pack2(x0.x,x0.y); a00.y = pack2(x0.z,x0.w);
      a00.z = pack2(x1v.x,x1v.y); a00.w = pack2(x1v.z,x1v.w);
      a01.x = pack2(x2.x,x2.y); a01.y = pack2(x2.z,x2.w);
      a01.z = pack2(x3.x,x3.y); a01.w = pack2(x3.z,x3.w);
      a10.x = pack2(y0.x,y0.y); a10.y = pack2(y0.z,y0.w);
      a10.z = pack2(y1v.x,y1v.y); a10.w = pack2(y1v.z,y1v.w);
      a11.x = pack2(y2.x,y2.y); a11.y = pack2(y2.z,y2.w);
      a11.z = pack2(y3.x,y3.y); a11.w = pack2(y3.z,y3.w);
    } else {
      const bf16* p0 = (const bf16*)A + r0 + kk + scol;
      const bf16* p1 = (const bf16*)A + r1 + kk + scol;
      a00 = *(const uint4*)p0;       a01 = *(const uint4*)(p0 + 8);
      a10 = *(const uint4*)p1;       a11 = *(const uint4*)(p1 + 8);
    }
    b00 = *(const uint4*)(BT + rB0 + kk + scol);
    b01 = *(const uint4*)(BT + rB0 + kk + scol + 8);
    b10 = *(const uint4*)(BT + rB1 + kk + scol);
    b11 = *(const uint4*)(BT + rB1 + kk + scol + 8);
    __syncthreads();
    *(uint4*)(As + srow*72 + scol)          = a00;
    *(uint4*)(As + srow*72 + scol + 8)      = a01;
    *(uint4*)(As + (64+srow)*72 + scol)     = a10;
    *(uint4*)(As + (64+srow)*72 + scol + 8) = a11;
    *(uint4*)(Bs + srow*72 + scol)          = b00;
    *(uint4*)(Bs + srow*72 + scol + 8)      = b01;
    *(uint4*)(Bs + (64+srow)*72 + scol)     = b10;
    *(uint4*)(Bs + (64+srow)*72 + scol + 8) = b11;
    __syncthreads();
    #pragma unroll
    for (int ks = 0; ks < 2; ks++){
      bh8 af[4], bfr[4];
      #pragma unroll
      for (int mt = 0; mt < 4; mt++)
        af[mt] = *reinterpret_cast<const bh8*>(As + (wr + mt*16 + lm)*72 + ks*32 + lq*8);
      #pragma unroll
      for (int nt = 0; nt < 4; nt++)
        bfr[nt] = *reinterpret_cast<const bh8*>(Bs + (wc + nt*16 + lm)*72 + ks*32 + lq*8);
      #pragma unroll
      for (int mt = 0; mt < 4; mt++)
        #pragma unroll
        for (int nt = 0; nt < 4; nt++)
          acc[mt][nt] = __builtin_amdgcn_mfma_f32_16x16x32_bf16(af[mt], bfr[nt], acc[mt][nt], 0, 0, 0);
    }
  }
  #pragma unroll
  for (int mt = 0; mt < 4; mt++)
    #pragma unroll
    for (int nt = 0; nt < 4; nt++)
      #pragma unroll
      for (int r = 0; r < 4; r++){
        int row = m0 + wr + mt*16 + lq*4 + r;
        int col = n0 + wc + nt*16 + lm;
        C[(size_t)row*256 + col] = __float2bfloat16(acc[mt][nt][r]);
      }
}

// ---- logits: block = 32 edges; staging+dot, then z=exp(l) and denom atomicAdd ----
__global__ __launch_bounds__(256) void k_logits(
    const bf16* __restrict__ He, const float* __restrict__ Pall,
    const float* __restrict__ bni, const float* __restrict__ bnj, const float* __restrict__ be,
    const float* __restrict__ ap, const int* __restrict__ ei,
    float* __restrict__ z, float* __restrict__ denom, int e0chunk)
{
  __shared__ float hs[32*264];
  __shared__ int   ssh[32], dsh[32];
  __shared__ float aps[256], bhs[256];
  int t = threadIdx.x;
  int base = e0chunk + blockIdx.x*32;
  if (t < 32) ssh[t] = ei[base + t];
  else if (t < 64) dsh[t-32] = ei[E_ + base + (t - 32)];
  aps[t] = ap[t];
  bhs[t] = bni[t] + bnj[t] + be[t];
  __syncthreads();
  int slot = (t >> 5)*33 + (t & 31);
  for (int r = 0; r < 32; r++){
    float v = b2f(He[(size_t)(base - e0chunk + r)*256 + t])
            + Pall[ssh[r]*768 + t] + Pall[dsh[r]*768 + 256 + t] + bhs[t];
    v = (v > 0.f) ? v : 0.2f*v;       // leaky_relu 0.2
    hs[r*264 + slot] = v;
  }
  __syncthreads();
  int e = t >> 3, h = t & 7;
  const float* hr  = hs + e*264 + h*33;
  const float* apr = aps + h*32;
  float acc = 0.f;
  #pragma unroll
  for (int i = 0; i < 32; i++) acc = fmaf(hr[i], apr[i], acc);
  float zv = __expf(fminf(acc, 30.f));
  z[(size_t)(base + e)*8 + h] = zv;
  atomicAdd(&denom[ssh[e]*8 + h], zv);
}

// ---- FUSED per-node aggregation: edge loop + matvecs + LN2 + Wq ----
__global__ __launch_bounds__(256) void k_agg(
    const int* __restrict__ offs, const int* __restrict__ eorder, const int* __restrict__ ei,
    const float* __restrict__ z,
    const void* __restrict__ ef,
    const float* __restrict__ Pall, const float* __restrict__ denom,
    const float* __restrict__ bmsg, const float* __restrict__ Wmsg,
    const void* __restrict__ nodes,
    const float* __restrict__ Wg, const float* __restrict__ bg,
    const float* __restrict__ g2, const float* __restrict__ b2v,
    const float* __restrict__ Wq, const float* __restrict__ bq,
    float* __restrict__ nodes1, float* __restrict__ qbuf)
{
  __shared__ float zsh[32*8];
  __shared__ int   esh[32];
  __shared__ int   dsh[32];
  __shared__ float Fs[8*257];
  __shared__ float aggs[256];
  __shared__ float sinv[8];
  __shared__ float r1[4], r2[4];
  __shared__ int dfsh;
  int n = blockIdx.x, t = threadIdx.x;
  bool isf32 = get_isf32(nodes, t, &dfsh);
  int h = t >> 5;
  int e0 = offs[n], e1 = offs[n+1];
  float facc[8] = {};
  float gacc = 0.f;
  int jz = t >> 3, hz = t & 7;
  for (int base = e0; base < e1; base += 32){
    int cnt = min(32, e1 - base);
    __syncthreads();
    if (t < 32){
      int e = (t < cnt) ? eorder[base + t] : eorder[e0];
      esh[t] = e;
      dsh[t] = ei[E_ + e];
    }
    __syncthreads();
    zsh[t] = (jz < cnt) ? z[(size_t)esh[jz]*8 + hz] : 0.f;
    __syncthreads();
    #pragma unroll 8
    for (int jj = 0; jj < 32; jj++){
      int e = esh[jj];
      float efv = ldf(ef, (size_t)e*256 + t, isf32);
      float pv  = Pall[(size_t)dsh[jj]*768 + 512 + t];
      #pragma unroll
      for (int hq = 0; hq < 8; hq++) facc[hq] = fmaf(zsh[jj*8 + hq], efv, facc[hq]);
      gacc = fmaf(zsh[jj*8 + h], pv, gacc);
    }
  }
  if (t < 8){
    float ds = denom[n*8 + t];
    sinv[t] = (ds > 0.f) ? 1.f/ds : 0.f;
  }
  __syncthreads();
  #pragma unroll
  for (int hq = 0; hq < 8; hq++)
    Fs[hq*257 + t] = facc[hq] * sinv[hq];
  __syncthreads();
  float am = gacc * sinv[h] + bmsg[t];
  const float* fr = Fs + h*257;
  {
    float p0=0.f, p1=0.f, p2=0.f, p3=0.f;
    for (int k = 0; k < 256; k += 4){
      p0 = fmaf(fr[k+0], Wmsg[(size_t)(256 + k + 0)*256 + t], p0);
      p1 = fmaf(fr[k+1], Wmsg[(size_t)(256 + k + 1)*256 + t], p1);
      p2 = fmaf(fr[k+2], Wmsg[(size_t)(256 + k + 2)*256 + t], p2);
      p3 = fmaf(fr[k+3], Wmsg[(size_t)(256 + k + 3)*256 + t], p3);
    }
    am += (p0 + p1) + (p2 + p3);
  }
  aggs[t] = am;
  __syncthreads();
  float o = bg[t] + ldf(nodes, (size_t)n*256 + t, isf32);
  {
    float p0=0.f, p1=0.f, p2=0.f, p3=0.f;
    for (int k = 0; k < 256; k += 4){
      p0 = fmaf(aggs[k+0], Wg[(k+0)*256 + t], p0);
      p1 = fmaf(aggs[k+1], Wg[(k+1)*256 + t], p1);
      p2 = fmaf(aggs[k+2], Wg[(k+2)*256 + t], p2);
      p3 = fmaf(aggs[k+3], Wg[(k+3)*256 + t], p3);
    }
    o += (p0 + p1) + (p2 + p3);
  }
  nodes1[n*256 + t] = o;
  float mu, rstd;
  ln_stats(o, t, r1, r2, mu, rstd);
  float x2 = (o - mu) * rstd * g2[t] + b2v[t];
  aggs[t] = x2;
  __syncthreads();
  float q = bq[t];
  {
    float p0=0.f, p1=0.f, p2=0.f, p3=0.f;
    for (int k = 0; k < 256; k += 4){
      p0 = fmaf(aggs[k+0], Wq[(k+0)*256 + t], p0);
      p1 = fmaf(aggs[k+1], Wq[(k+1)*256 + t], p1);
      p2 = fmaf(aggs[k+2], Wq[(k+2)*256 + t], p2);
      p3 = fmaf(aggs[k+3], Wq[(k+3)*256 + t], p3);
    }
    q += (p0 + p1) + (p2 + p3);
  }
  qbuf[n*256 + t] = q;
}

// ---- cross attention: block per (qtile=8, h, b); writes Y bf16 scrambled ----
__global__ __launch_bounds__(256) void k_attn(
    const float* __restrict__ qbuf, const float* __restrict__ kbuf, const float* __restrict__ vT,
    const bf16* __restrict__ bias, bf16* __restrict__ Yb)
{
  __shared__ float Qs[8*33];
  __shared__ float Ks[128*33];
  __shared__ float Sc[8*1024];
  __shared__ float Op[4*8*32];
  __shared__ float qs[8];
  int qt = blockIdx.x, h = blockIdx.y, b = blockIdx.z;
  int q0 = qt*8;
  int t = threadIdx.x;
  {
    int q = t >> 5, d = t & 31;
    int gq = q0 + q;
    Qs[q*33 + d] = (gq < NQ_) ? qbuf[((size_t)b*NQ_ + gq)*256 + h*32 + d] : 0.f;
  }
  const float* kbase = kbuf + (size_t)b*NK_*256 + h*32;
  const bf16*  bb    = bias + ((size_t)(b*NH_ + h)*NQ_)*NK_;
  int kl = t & 127;
  int qb = (t >> 7) * 4;
  for (int kt = 0; kt < 8; kt++){
    int k0 = kt*128;
    __syncthreads();
    {
      int r = t >> 1, c0 = (t & 1) * 16;
      const float* src = kbase + (size_t)(k0 + r)*256 + c0;
      float* dst = Ks + r*33 + c0;
      #pragma unroll
      for (int ii = 0; ii < 4; ii++){
        float4 f = *(const float4*)(src + ii*4);
        dst[ii*4+0]=f.x; dst[ii*4+1]=f.y; dst[ii*4+2]=f.z; dst[ii*4+3]=f.w;
      }
    }
    __syncthreads();
    float a0=0.f, a1=0.f, a2=0.f, a3=0.f;
    const float* kr = Ks + kl*33;
    #pragma unroll
    for (int i = 0; i < 32; i++){
      float kd = kr[i];
      a0 = fmaf(kd, Qs[(qb+0)*33+i], a0);
      a1 = fmaf(kd, Qs[(qb+1)*33+i], a1);
      a2 = fmaf(kd, Qs[(qb+2)*33+i], a2);
      a3 = fmaf(kd, Qs[(qb+3)*33+i], a3);
    }
    float av[4] = {a0,a1,a2,a3};
    #pragma unroll
    for (int j = 0; j < 4; j++){
      int gq = min(q0 + qb + j, NQ_-1);
      float s = av[j]*0.17677669529663689f + b2f(bb[(size_t)gq*NK_ + k0 + kl]);
      Sc[(qb+j)*1024 + k0 + kl] = s;
    }
  }
  __syncthreads();
  {
    int q = t >> 5, j = t & 31;
    float m = -1e30f;
    for (int k = j; k < 1024; k += 32) m = fmaxf(m, Sc[q*1024 + k]);
    #pragma unroll
    for (int o = 16; o; o >>= 1) m = fmaxf(m, __shfl_xor(m, o));
    float ssum = 0.f;
    for (int k = j; k < 1024; k += 32){
      float e = __expf(Sc[q*1024 + k] - m);
      Sc[q*1024 + k] = e;
      ssum += e;
    }
    #pragma unroll
    for (int o = 16; o; o >>= 1) ssum += __shfl_xor(ssum, o);
    if (j == 0) qs[q] = ssum;
  }
  int d = t & 31, qg = (t >> 5) & 1, ks = t >> 6;
  const float* vrb = vT + (((size_t)(b*NH_ + h))*32)*NK_;
  float o0=0.f, o1=0.f, o2=0.f, o3=0.f;
  for (int kt = 0; kt < 8; kt++){
    int k0 = kt*128;
    __syncthreads();
    {
      int d2 = t >> 3, kq = (t & 7) * 16;
      const float* src = vrb + (size_t)d2*NK_ + k0 + kq;
      #pragma unroll
      for (int ii = 0; ii < 4; ii++){
        float4 f = *(const float4*)(src + ii*4);
        Ks[(kq+ii*4+0)*33 + d2] = f.x;
        Ks[(kq+ii*4+1)*33 + d2] = f.y;
        Ks[(kq+ii*4+2)*33 + d2] = f.z;
        Ks[(kq+ii*4+3)*33 + d2] = f.w;
      }
    }
    __syncthreads();
    const float* sc0 = Sc + (qg*4+0)*1024 + k0 + ks*32;
    const float* sc1 = Sc + (qg*4+1)*1024 + k0 + ks*32;
    const float* sc2 = Sc + (qg*4+2)*1024 + k0 + ks*32;
    const float* sc3 = Sc + (qg*4+3)*1024 + k0 + ks*32;
    #pragma unroll
    for (int kk = 0; kk < 32; kk++){
      float vv = Ks[(ks*32+kk)*33 + d];
      o0 = fmaf(sc0[kk], vv, o0);
      o1 = fmaf(sc1[kk], vv, o1);
      o2 = fmaf(sc2[kk], vv, o2);
      o3 = fmaf(sc3[kk], vv, o3);
    }
  }
  Op[((ks*8) + qg*4 + 0)*32 + d] = o0;
  Op[((ks*8) + qg*4 + 1)*32 + d] = o1;
  Op[((ks*8) + qg*4 + 2)*32 + d] = o2;
  Op[((ks*8) + qg*4 + 3)*32 + d] = o3;
  __syncthreads();
  {
    int q = t >> 5, dd = t & 31;
    int gq = q0 + q;
    if (gq < NQ_){
      float s = Op[(0*8+q)*32+dd] + Op[(1*8+q)*32+dd]
              + Op[(2*8+q)*32+dd] + Op[(3*8+q)*32+dd];
      float sv = s / qs[q];
      int tt = h*NQ_ + gq;
      Yb[((size_t)b*NQ_ + (tt >> 3))*256 + (tt & 7)*32 + dd] = __float2bfloat16(sv);
    }
  }
}

// ---- LN3: n2 -> x3 (f32 + bf16) ----
__global__ __launch_bounds__(256) void k_ln3(
    const float* __restrict__ n2, const float* __restrict__ g3, const float* __restrict__ b3,
    float* __restrict__ x3f, bf16* __restrict__ x3b)
{
  __shared__ float r1[4], r2[4];
  int n = blockIdx.x, t = threadIdx.x;
  float v = n2[n*256 + t];
  float mu, rstd;
  ln_stats(v, t, r1, r2, mu, rstd);
  float x3 = (v - mu) * rstd * g3[t] + b3[t];
  x3f[n*256 + t] = x3;
  x3b[n*256 + t] = __float2bfloat16(x3);
}

extern "C" void kernel_launch(void* const* d_in, const int* in_sizes, int n_in,
                              void* d_out, int out_size, void* d_ws, size_t ws_size,
                              hipStream_t stream)
{
  const void* nodes  = d_in[0];
  const void* images = d_in[1];
  const void* rel    = d_in[2];
  const void* ef     = d_in[3];
  const int*  ei     = (const int*)d_in[4];
  float* out = (float*)d_out;

  char* w = (char*)d_ws;
  auto alloc = [&](size_t bytes) -> void* {
    void* p = (void*)w; w += (bytes + 255) & ~(size_t)255; return p;
  };
  float*    Wall   = (float*)   alloc((size_t)WTOT*4);                 //  4.75 MB
  bf16*     Wbt    = (bf16*)    alloc((size_t)983040*2);               //  1.97 MB
  bf16*     bias   = (bf16*)    alloc((size_t)NB_*NH_*NQ_*NK_*2);      //  9.8 MB
  float*    zbuf   = (float*)   alloc((size_t)E_*8*4);                 //  4.2 MB
  float*    Pall   = (float*)   alloc((size_t)N_*768*4);               //  1.8 MB
  float*    nodes1 = (float*)   alloc(N_*256*4);
  float*    qbuf   = (float*)   alloc(N_*256*4);
  float*    kbuf   = (float*)   alloc((size_t)NB_*NK_*256*4);          //  2.1 MB
  float*    vT     = (float*)   alloc((size_t)NB_*NH_*32*NK_*4);       //  2.1 MB
  float*    n2buf  = (float*)   alloc(N_*256*4);
  float*    x3f    = (float*)   alloc(N_*256*4);
  bf16*     x1     = (bf16*)    alloc(N_*256*2);
  bf16*     x3b    = (bf16*)    alloc(N_*256*2);
  bf16*     Yb     = (bf16*)    alloc(N_*256*2);
  bf16*     H1     = (bf16*)    alloc((size_t)N_*1024*2);              //  1.2 MB
  float*    denom  = (float*)   alloc(N_*8*4);
  int*      offs   = (int*)     alloc((N_+1)*4);
  int*      cursor = (int*)     alloc(N_*4);
  int*      eorder = (int*)     alloc((size_t)E_*4);                   //  0.5 MB
  // base total ~= 32 MB; He sized adaptively from remaining workspace
  size_t used = (size_t)(w - (char*)d_ws);
  int CH = E_;
  while (CH > 2048 && used + (size_t)CH*256*2 + 256 > ws_size) CH >>= 1;
  bf16* He = (bf16*)alloc((size_t)CH*256*2);

  // Wbt sub-buffers
  bf16* WeT  = Wbt + 0;
  bf16* WkvT = Wbt + 65536;
  bf16* WnpT = Wbt + 196608;
  bf16* WcoT = Wbt + 393216;
  bf16* Wf1T = Wbt + 458752;
  bf16* Wf2T = Wbt + 720896;

  const float *ln2g=Wall+WOFF[2],  *ln2b=Wall+WOFF[3];
  const float *ln3g=Wall+WOFF[4],  *ln3b=Wall+WOFF[5];
  const float *bni=Wall+WOFF[7],  *bnj=Wall+WOFF[9], *be=Wall+WOFF[10];
  const float *ap =Wall+WOFF[11];
  const float *Wmsg=Wall+WOFF[12], *bmsg=Wall+WOFF[13];
  const float *Wg=Wall+WOFF[14], *bg=Wall+WOFF[15];
  const float *Wq=Wall+WOFF[16], *bq=Wall+WOFF[17];
  const float *bkv=Wall+WOFF[19];
  const float *Wc1=Wall+WOFF[20], *bc1=Wall+WOFF[21];
  const float *Wc2=Wall+WOFF[22], *bc2=Wall+WOFF[23];
  const float *bco=Wall+WOFF[25];
  const float *bf1v=Wall+WOFF[27];
  const float *bf2v=Wall+WOFF[29];

  SrcTab tab;
  {
    const int idx[NWSEG] = {6,7,8,9,10,11, 12,13,14,15, 17,18, 19,20, 21,22,23,24,
                            25,26, 27,28,29,30, 31,32, 33,34,35,36, 16};
    for (int i = 0; i < NWSEG; i++) tab.p[i] = d_in[idx[i]];
  }
  TrTabP trp;
  // transpose tiles read RAW source tensors (dual-dtype), no Wall dependency
  trp.p[0] = d_in[16]; trp.d[0] = {0, 256,  256, 0};            // We   -> WeT
  trp.p[1] = d_in[25]; trp.d[1] = {0, 256,  512, 65536};        // Wkv  -> WkvT
  trp.p[2] = d_in[12]; trp.d[2] = {0, 256,  256, 196608};       // Wni  -> WnpT[0:256]
  trp.p[3] = d_in[14]; trp.d[3] = {0, 256,  256, 196608+65536}; // Wnj  -> WnpT[256:512]
  trp.p[4] = d_in[19]; trp.d[4] = {0, 256,  256, 196608+131072};// Wmsg0-> WnpT[512:768]
  trp.p[5] = d_in[31]; trp.d[5] = {0, 256,  256, 393216};       // Wco  -> WcoT
  trp.p[6] = d_in[33]; trp.d[6] = {0, 256, 1024, 458752};       // Wf1  -> Wf1T
  trp.p[7] = d_in[35]; trp.d[7] = {0,1024,  256, 720896};       // Wf2  -> Wf2T

  // 1: cvt + tr + ln1 + denom-zero (all independent, per-block dtype sniff)
  k_prep <<<PB_TOTAL, 256, 0, stream>>>(tab, trp, Wall, Wbt, nodes, x1, denom);
  // 2: count+scan (single block)
  k_scan <<<1, 1024, 0, stream>>>(ei, offs, cursor);
  // 3: Pall-gemm | kv-gemm | cpb | scatter (independent, one dispatch)
  k_batch<<<BB_TOTAL, 256, 0, stream>>>(x1, WnpT, Pall, images, WkvT,
                                        kbuf, vT, bkv, rel, Wc1, bc1, Wc2, bc2,
                                        bias, ei, cursor, eorder, nodes);
  // 4,5: He GEMM + logits
  for (int c0 = 0; c0 < E_; c0 += CH){
    k_gemm_dual<<<dim3(CH/128, 2), 256, 0, stream>>>(ef, c0, nodes, WeT, He);
    k_logits   <<<CH/32, 256, 0, stream>>>(He, Pall, bni, bnj, be, ap, ei,
                                           zbuf, denom, c0);
  }
  // 6: fused edge aggregation + per-node matvecs + LN2 + Wq
  k_agg  <<<N_, 256, 0, stream>>>(offs, eorder, ei, zbuf, ef, Pall, denom,
                                  bmsg, Wmsg, nodes, Wg, bg, ln2g, ln2b, Wq, bq,
                                  nodes1, qbuf);
  // 7: attention
  dim3 agrid((NQ_ + 7)/8, NH_, NB_);
  k_attn <<<agrid, 256, 0, stream>>>(qbuf, kbuf, vT, bias, Yb);
  // 8: out-proj + residual
  k_gemm <<<dim3(5,2), 256, 0, stream>>>(Yb, 256, N_, WcoT, 2,
                                         n2buf, 256, bco, nodes1, nullptr);
  // 9: LN3
  k_ln3  <<<N_, 256, 0, stream>>>(n2buf, ln3g, ln3b, x3f, x3b);
  // 10,11: FFN
  k_gemm <<<dim3(5,8), 256, 0, stream>>>(x3b, 256, N_, Wf1T, 3,
                                         H1, 1024, bf1v, nullptr, nullptr);
  k_gemm <<<dim3(5,2), 256, 0, stream>>>(H1, 1024, N_, Wf2T, 2,
                                         out, 256, bf2v, x3f, nullptr);
}

// Round 8
// 702.614 us; speedup vs baseline: 1.0463x; 1.0463x over previous
//
#include <hip/hip_runtime.h>
#include <hip/hip_bf16.h>
#include <math.h>

// Problem constants
#define E_   131072
#define N_   600
#define NB_  2
#define NQ_  300
#define NK_  1024
#define NH_  8

typedef __hip_bfloat16 bf16;
typedef __bf16 bh8 __attribute__((ext_vector_type(8)));
typedef float  fx4 __attribute__((ext_vector_type(4)));

static __device__ __forceinline__ float b2f(bf16 x){ return __bfloat162float(x); }
static __device__ __forceinline__ float bfbits2f(unsigned short u){
  return __uint_as_float((unsigned)u << 16);
}
static __device__ __forceinline__ unsigned short bfu(float x){
  return __bfloat16_as_ushort(__float2bfloat16(x));
}
static __device__ __forceinline__ unsigned pack2(float x, float y){
  return (unsigned)bfu(x) | ((unsigned)bfu(y) << 16);
}
// dual-dtype scalar load: isf32 ? f32[i] : bf16[i]
static __device__ __forceinline__ float ldf(const void* p, size_t i, bool isf32){
  return isf32 ? ((const float*)p)[i] : b2f(((const bf16*)p)[i]);
}

// per-block dtype sniff: wave 0 examines first 64 ushorts of nodes,
// broadcasts via LDS. No k_init dispatch, no dflag buffer.
static __device__ __forceinline__ bool get_isf32(const void* nodes, int t, int* sh){
  if (t < 64){
    const unsigned short* h = (const unsigned short*)nodes;
    int e = (h[t] >> 7) & 0xFF;
    unsigned long long b = __ballot(e < 100 || e > 150);
    if (t == 0) *sh = (__popcll(b) > 8) ? 1 : 0;
  }
  __syncthreads();
  return *sh != 0;
}

// ---- converted-weight table offsets (elements); seg 30 = We ----
constexpr int WOFF[32] = {
  0,256,512,768,1024,1280,
  1536,67072,67328,132864,
  133120,133376,
  133632,264704,
  264960,330496,330752,396288,
  396544,527616,
  528128,528640,528896,530944,
  530952,596488,
  596744,858888,859912,1122056,
  1122312,
  1187848};
#define NWSEG 31
#define WTOT  1187848
struct SrcTab { const void* p[NWSEG]; };
struct TrTabP { const void* p[8]; int4 d[8]; };  // y=K, z=N, w=dstOff(Wbt)

// block-wide LayerNorm stats over 256 values (one per thread), 4 waves
static __device__ __forceinline__ void ln_stats(float v, int t, float* r1, float* r2,
                                                float& mu, float& rstd){
  float s1 = v, s2 = v*v;
  #pragma unroll
  for (int o = 32; o; o >>= 1){ s1 += __shfl_down(s1, o); s2 += __shfl_down(s2, o); }
  if ((t & 63) == 0){ r1[t>>6] = s1; r2[t>>6] = s2; }
  __syncthreads();
  float t1 = r1[0]+r1[1]+r1[2]+r1[3];
  float t2 = r2[0]+r2[1]+r2[2]+r2[3];
  mu = t1 * (1.f/256.f);
  float var = t2 * (1.f/256.f) - mu*mu;
  rstd = rsqrtf(var + 1e-5f);
  __syncthreads();
}

// ======== MEGA PREP: cvt | tr | ln1 | denom/cnt-zero in ONE dispatch ========
#define PB_CVT 4641
#define PB_TR  2048
#define PB_LN1 600
#define PB_DEN 19
#define PB_TOTAL (PB_CVT + PB_TR + PB_LN1 + PB_DEN)

__global__ __launch_bounds__(256) void k_prep(
    SrcTab tab, TrTabP trp, float* __restrict__ wall, bf16* __restrict__ wbt,
    const void* __restrict__ nodes, bf16* __restrict__ x1,
    float* __restrict__ denom, int* __restrict__ cnt)
{
  __shared__ float tile[64][65];
  __shared__ float r1[4], r2[4];
  __shared__ int dsh;
  int t = threadIdx.x;
  int b = blockIdx.x;
  bool isf32 = get_isf32(nodes, t, &dsh);
  if (b < PB_CVT){
    int i = b*256 + t;
    if (i < WTOT){
      int seg = 0;
      while (seg < NWSEG-1 && i >= WOFF[seg+1]) seg++;
      wall[i] = ldf(tab.p[seg], (size_t)(i - WOFF[seg]), isf32);
    }
  } else if (b < PB_CVT + PB_TR){
    // 64x64 transpose tiles, reading RAW sources via ldf (no Wall dep)
    int lb = b - PB_CVT;
    int bz = lb >> 8, by = (lb >> 4) & 15, bx = lb & 15;
    int4 d = trp.d[bz];
    int K = d.y, Nn = d.z;
    int k0 = bx*64, n0 = by*64;
    if (k0 < K && n0 < Nn){
      const void* src = trp.p[bz];
      bf16* dst = wbt + d.w;
      int rr = t >> 6, cc = t & 63;
      #pragma unroll
      for (int p = 0; p < 16; p++){
        int row = p*4 + rr;
        tile[row][cc] = ldf(src, (size_t)(k0 + row)*Nn + n0 + cc, isf32);
      }
      __syncthreads();
      #pragma unroll
      for (int p = 0; p < 16; p++){
        int row = p*4 + rr;
        dst[(size_t)(n0 + row)*K + k0 + cc] = __float2bfloat16(tile[cc][row]);
      }
    }
  } else if (b < PB_CVT + PB_TR + PB_LN1){
    int n = b - (PB_CVT + PB_TR);
    float v = ldf(nodes, (size_t)n*256 + t, isf32);
    float mu, rstd;
    ln_stats(v, t, r1, r2, mu, rstd);
    float g  = ldf(tab.p[0], t, isf32);   // ln1_g = d_in[6]
    float bb = ldf(tab.p[1], t, isf32);   // ln1_b = d_in[7]
    x1[n*256 + t] = __float2bfloat16((v - mu) * rstd * g + bb);
  } else {
    int i = (b - (PB_CVT + PB_TR + PB_LN1))*256 + t;
    if (i < N_*NH_) denom[i] = 0.f;
    if (i < N_) cnt[i] = 0;
  }
}

__global__ void k_count(const int* __restrict__ ei, int* cnt){
  int e = blockIdx.x*256 + threadIdx.x;
  atomicAdd(&cnt[ei[e]], 1);
}

__global__ __launch_bounds__(1024) void k_scan(const int* __restrict__ cnt,
                                               int* offs, int* cursor){
  __shared__ int s[1024];
  int t = threadIdx.x;
  s[t] = (t < N_) ? cnt[t] : 0;
  __syncthreads();
  for (int o = 1; o < 1024; o <<= 1){
    int v = 0;
    if (t >= o) v = s[t - o];
    __syncthreads();
    if (t >= o) s[t] += v;
    __syncthreads();
  }
  if (t < N_){ int excl = (t == 0) ? 0 : s[t-1]; offs[t] = excl; cursor[t] = excl; }
  if (t == N_-1) offs[N_] = s[N_-1];
}

__global__ void k_scatter(const int* __restrict__ ei, int* cursor, int* eorder){
  int e = blockIdx.x*256 + threadIdx.x;
  int pos = atomicAdd(&cursor[ei[e]], 1);
  eorder[pos] = e;
}

// ======== generic MFMA GEMM body (BK=64), shared-memory passed in ========
static __device__ void gemm_body(
    const void* __restrict__ A, bool f32src, int K, int M,
    const bf16* __restrict__ BT, int mode,
    void* __restrict__ D, int ldd,
    const float* __restrict__ bias, const float* __restrict__ add,
    float* __restrict__ aux,
    int bx, int by, int t, bf16* As, bf16* Bs)
{
  int m0 = bx * 128;
  int n0 = by * 128;
  int wave = t >> 6, lane = t & 63;
  int wr = (wave >> 1) * 64, wc = (wave & 1) * 64;
  int lm = lane & 15, lq = lane >> 4;
  int srow = t >> 2;
  int scol = (t & 3) * 16;
  size_t rA0 = (size_t)(m0 + srow) * K;
  size_t rA1 = (size_t)(m0 + 64 + srow) * K;
  size_t rB0 = (size_t)(n0 + srow) * K;
  size_t rB1 = (size_t)(n0 + 64 + srow) * K;
  fx4 acc[4][4] = {};
  for (int kk = 0; kk < K; kk += 64){
    uint4 a00, a01, a10, a11, b00, b01, b10, b11;
    if (f32src){
      const float* p0 = (const float*)A + rA0 + kk + scol;
      const float* p1 = (const float*)A + rA1 + kk + scol;
      float4 x0 = *(const float4*)p0,      x1v = *(const float4*)(p0 + 4);
      float4 x2 = *(const float4*)(p0 + 8), x3 = *(const float4*)(p0 + 12);
      float4 y0 = *(const float4*)p1,      y1v = *(const float4*)(p1 + 4);
      float4 y2 = *(const float4*)(p1 + 8), y3 = *(const float4*)(p1 + 12);
      a00.x = pack2(x0.x,x0.y); a00.y = pack2(x0.z,x0.w);
      a00.z = pack2(x1v.x,x1v.y); a00.w = pack2(x1v.z,x1v.w);
      a01.x = pack2(x2.x,x2.y); a01.y = pack2(x2.z,x2.w);
      a01.z = pack2(x3.x,x3.y); a01.w = pack2(x3.z,x3.w);
      a10.x = pack2(y0.x,y0.y); a10.y = pack2(y0.z,y0.w);
      a10.z = pack2(y1v.x,y1v.y); a10.w = pack2(y1v.z,y1v.w);
      a11.x = pack2(y2.x,y2.y); a11.y = pack2(y2.z,y2.w);
      a11.z = pack2(y3.x,y3.y); a11.w = pack2(y3.z,y3.w);
    } else {
      const bf16* p0 = (const bf16*)A + rA0 + kk + scol;
      const bf16* p1 = (const bf16*)A + rA1 + kk + scol;
      a00 = *(const uint4*)p0;       a01 = *(const uint4*)(p0 + 8);
      a10 = *(const uint4*)p1;       a11 = *(const uint4*)(p1 + 8);
    }
    b00 = *(const uint4*)(BT + rB0 + kk + scol);
    b01 = *(const uint4*)(BT + rB0 + kk + scol + 8);
    b10 = *(const uint4*)(BT + rB1 + kk + scol);
    b11 = *(const uint4*)(BT + rB1 + kk + scol + 8);
    __syncthreads();
    *(uint4*)(As + srow*72 + scol)          = a00;
    *(uint4*)(As + srow*72 + scol + 8)      = a01;
    *(uint4*)(As + (64+srow)*72 + scol)     = a10;
    *(uint4*)(As + (64+srow)*72 + scol + 8) = a11;
    *(uint4*)(Bs + srow*72 + scol)          = b00;
    *(uint4*)(Bs + srow*72 + scol + 8)      = b01;
    *(uint4*)(Bs + (64+srow)*72 + scol)     = b10;
    *(uint4*)(Bs + (64+srow)*72 + scol + 8) = b11;
    __syncthreads();
    #pragma unroll
    for (int ks = 0; ks < 2; ks++){
      bh8 af[4], bfr[4];
      #pragma unroll
      for (int mt = 0; mt < 4; mt++)
        af[mt] = *reinterpret_cast<const bh8*>(As + (wr + mt*16 + lm)*72 + ks*32 + lq*8);
      #pragma unroll
      for (int nt = 0; nt < 4; nt++)
        bfr[nt] = *reinterpret_cast<const bh8*>(Bs + (wc + nt*16 + lm)*72 + ks*32 + lq*8);
      #pragma unroll
      for (int mt = 0; mt < 4; mt++)
        #pragma unroll
        for (int nt = 0; nt < 4; nt++)
          acc[mt][nt] = __builtin_amdgcn_mfma_f32_16x16x32_bf16(af[mt], bfr[nt], acc[mt][nt], 0, 0, 0);
    }
  }
  #pragma unroll
  for (int mt = 0; mt < 4; mt++)
    #pragma unroll
    for (int nt = 0; nt < 4; nt++)
      #pragma unroll
      for (int r = 0; r < 4; r++){
        int row = m0 + wr + mt*16 + lq*4 + r;
        int col = n0 + wc + nt*16 + lm;
        if (row >= M) continue;
        float v = acc[mt][nt][r];
        if (mode == 0){
          if (bias) v += bias[col];
          ((float*)D)[(size_t)row*ldd + col] = v;
        } else if (mode == 1){
          v += bias[col];
          if (col < 256){
            ((float*)D)[(size_t)row*256 + col] = v;
          } else {
            int b = row >> 10, ki = row & 1023;
            int hh = (col - 256) >> 5, dd = (col - 256) & 31;
            aux[(((size_t)b*NH_ + hh)*32 + dd)*NK_ + ki] = v;
          }
        } else if (mode == 2){
          v += bias[col] + add[(size_t)row*ldd + col];
          ((float*)D)[(size_t)row*ldd + col] = v;
        } else {
          v += bias[col];
          float g = 0.5f*v*(1.f + erff(v*0.70710678118654752f));
          ((bf16*)D)[(size_t)row*ldd + col] = __float2bfloat16(g);
        }
      }
}

// standalone GEMM wrapper; adual selects dual-dtype A (via sniff)
__global__ __launch_bounds__(256) void k_gemm(
    const void* __restrict__ A, int adual, const void* __restrict__ nodes,
    int K, int M, const bf16* __restrict__ BT, int mode,
    void* __restrict__ D, int ldd,
    const float* __restrict__ bias, const float* __restrict__ add,
    float* __restrict__ aux)
{
  __shared__ __align__(16) bf16 As[128*72];
  __shared__ __align__(16) bf16 Bs[128*72];
  __shared__ int dsh;
  int t = threadIdx.x;
  bool isf32 = get_isf32(nodes, t, &dsh) && (adual != 0);
  gemm_body(A, isf32, K, M, BT, mode, D, ldd, bias, add, aux,
            blockIdx.x, blockIdx.y, t, As, Bs);
}

// ---- He GEMM (dual-dtype A), bf16 out. BK=64, per-block dtype sniff ----
__global__ __launch_bounds__(256) void k_gemm_dual(
    const void* __restrict__ A, int m_base, const void* __restrict__ nodes,
    const bf16* __restrict__ BT, bf16* __restrict__ C)
{
  __shared__ __align__(16) bf16 As[128*72];
  __shared__ __align__(16) bf16 Bs[128*72];
  __shared__ int dsh;
  int t = threadIdx.x;
  bool isf32 = get_isf32(nodes, t, &dsh);
  int m0 = blockIdx.x * 128;
  int n0 = blockIdx.y * 128;
  int wave = t >> 6, lane = t & 63;
  int wr = (wave >> 1) * 64, wc = (wave & 1) * 64;
  int lm = lane & 15, lq = lane >> 4;
  int srow = t >> 2;
  int scol = (t & 3) * 16;
  size_t r0  = (size_t)(m_base + m0 + srow) * 256;
  size_t r1  = (size_t)(m_base + m0 + 64 + srow) * 256;
  size_t rB0 = (size_t)(n0 + srow) * 256;
  size_t rB1 = (size_t)(n0 + 64 + srow) * 256;
  fx4 acc[4][4] = {};
  for (int kk = 0; kk < 256; kk += 64){
    uint4 a00, a01, a10, a11, b00, b01, b10, b11;
    if (isf32){
      const float* p0 = (const float*)A + r0 + kk + scol;
      const float* p1 = (const float*)A + r1 + kk + scol;
      float4 x0 = *(const float4*)p0,      x1v = *(const float4*)(p0 + 4);
      float4 x2 = *(const float4*)(p0 + 8), x3 = *(const float4*)(p0 + 12);
      float4 y0 = *(const float4*)p1,      y1v = *(const float4*)(p1 + 4);
      float4 y2 = *(const float4*)(p1 + 8), y3 = *(const float4*)(p1 + 12);
      a00.x = pack2(x0.x,x0.y); a00.y = pack2(x0.z,x0.w);
      a00.z = pack2(x1v.x,x1v.y); a00.w = pack2(x1v.z,x1v.w);
      a01.x = pack2(x2.x,x2.y); a01.y = pack2(x2.z,x2.w);
      a01.z = pack2(x3.x,x3.y); a01.w = pack2(x3.z,x3.w);
      a10.x = pack2(y0.x,y0.y); a10.y = pack2(y0.z,y0.w);
      a10.z = pack2(y1v.x,y1v.y); a10.w = pack2(y1v.z,y1v.w);
      a11.x = pack2(y2.x,y2.y); a11.y = pack2(y2.z,y2.w);
      a11.z = pack2(y3.x,y3.y); a11.w = pack2(y3.z,y3.w);
    } else {
      const bf16* p0 = (const bf16*)A + r0 + kk + scol;
      const bf16* p1 = (const bf16*)A + r1 + kk + scol;
      a00 = *(const uint4*)p0;       a01 = *(const uint4*)(p0 + 8);
      a10 = *(const uint4*)p1;       a11 = *(const uint4*)(p1 + 8);
    }
    b00 = *(const uint4*)(BT + rB0 + kk + scol);
    b01 = *(const uint4*)(BT + rB0 + kk + scol + 8);
    b10 = *(const uint4*)(BT + rB1 + kk + scol);
    b11 = *(const uint4*)(BT + rB1 + kk + scol + 8);
    __syncthreads();
    *(uint4*)(As + srow*72 + scol)          = a00;
    *(uint4*)(As + srow*72 + scol + 8)      = a01;
    *(uint4*)(As + (64+srow)*72 + scol)     = a10;
    *(uint4*)(As + (64+srow)*72 + scol + 8) = a11;
    *(uint4*)(Bs + srow*72 + scol)          = b00;
    *(uint4*)(Bs + srow*72 + scol + 8)      = b01;
    *(uint4*)(Bs + (64+srow)*72 + scol)     = b10;
    *(uint4*)(Bs + (64+srow)*72 + scol + 8) = b11;
    __syncthreads();
    #pragma unroll
    for (int ks = 0; ks < 2; ks++){
      bh8 af[4], bfr[4];
      #pragma unroll
      for (int mt = 0; mt < 4; mt++)
        af[mt] = *reinterpret_cast<const bh8*>(As + (wr + mt*16 + lm)*72 + ks*32 + lq*8);
      #pragma unroll
      for (int nt = 0; nt < 4; nt++)
        bfr[nt] = *reinterpret_cast<const bh8*>(Bs + (wc + nt*16 + lm)*72 + ks*32 + lq*8);
      #pragma unroll
      for (int mt = 0; mt < 4; mt++)
        #pragma unroll
        for (int nt = 0; nt < 4; nt++)
          acc[mt][nt] = __builtin_amdgcn_mfma_f32_16x16x32_bf16(af[mt], bfr[nt], acc[mt][nt], 0, 0, 0);
    }
  }
  #pragma unroll
  for (int mt = 0; mt < 4; mt++)
    #pragma unroll
    for (int nt = 0; nt < 4; nt++)
      #pragma unroll
      for (int r = 0; r < 4; r++){
        int row = m0 + wr + mt*16 + lq*4 + r;
        int col = n0 + wc + nt*16 + lm;
        C[(size_t)row*256 + col] = __float2bfloat16(acc[mt][nt][r]);
      }
}

// ---- logits: block = 32 edges; staging+dot, then z=exp(l) and denom atomicAdd ----
__global__ __launch_bounds__(256) void k_logits(
    const bf16* __restrict__ He, const float* __restrict__ Pall,
    const float* __restrict__ bni, const float* __restrict__ bnj, const float* __restrict__ be,
    const float* __restrict__ ap, const int* __restrict__ ei,
    float* __restrict__ z, float* __restrict__ denom, int e0chunk)
{
  __shared__ float hs[32*264];
  __shared__ int   ssh[32], dsh[32];
  __shared__ float aps[256], bhs[256];
  int t = threadIdx.x;
  int base = e0chunk + blockIdx.x*32;
  if (t < 32) ssh[t] = ei[base + t];
  else if (t < 64) dsh[t-32] = ei[E_ + base + (t - 32)];
  aps[t] = ap[t];
  bhs[t] = bni[t] + bnj[t] + be[t];
  __syncthreads();
  int slot = (t >> 5)*33 + (t & 31);
  for (int r = 0; r < 32; r++){
    float v = b2f(He[(size_t)(base - e0chunk + r)*256 + t])
            + Pall[ssh[r]*768 + t] + Pall[dsh[r]*768 + 256 + t] + bhs[t];
    v = (v > 0.f) ? v : 0.2f*v;       // leaky_relu 0.2
    hs[r*264 + slot] = v;
  }
  __syncthreads();
  int e = t >> 3, h = t & 7;
  const float* hr  = hs + e*264 + h*33;
  const float* apr = aps + h*32;
  float acc = 0.f;
  #pragma unroll
  for (int i = 0; i < 32; i++) acc = fmaf(hr[i], apr[i], acc);
  float zv = __expf(fminf(acc, 30.f));
  z[(size_t)(base + e)*8 + h] = zv;
  atomicAdd(&denom[ssh[e]*8 + h], zv);
}

// ---- FUSED per-node aggregation: edge loop + matvecs + LN2 + Wq ----
__global__ __launch_bounds__(256) void k_agg(
    const int* __restrict__ offs, const int* __restrict__ eorder, const int* __restrict__ ei,
    const float* __restrict__ z,
    const void* __restrict__ ef,
    const float* __restrict__ Pall, const float* __restrict__ denom,
    const float* __restrict__ bmsg, const float* __restrict__ Wmsg,
    const void* __restrict__ nodes,
    const float* __restrict__ Wg, const float* __restrict__ bg,
    const float* __restrict__ g2, const float* __restrict__ b2v,
    const float* __restrict__ Wq, const float* __restrict__ bq,
    float* __restrict__ nodes1, float* __restrict__ qbuf)
{
  __shared__ float zsh[32*8];
  __shared__ int   esh[32];
  __shared__ int   dsh[32];
  __shared__ float Fs[8*257];
  __shared__ float aggs[256];
  __shared__ float sinv[8];
  __shared__ float r1[4], r2[4];
  __shared__ int dfsh;
  int n = blockIdx.x, t = threadIdx.x;
  bool isf32 = get_isf32(nodes, t, &dfsh);
  int h = t >> 5;
  int e0 = offs[n], e1 = offs[n+1];
  float facc[8] = {};
  float gacc = 0.f;
  int jz = t >> 3, hz = t & 7;
  for (int base = e0; base < e1; base += 32){
    int cnt = min(32, e1 - base);
    __syncthreads();
    if (t < 32){
      int e = (t < cnt) ? eorder[base + t] : eorder[e0];
      esh[t] = e;
      dsh[t] = ei[E_ + e];
    }
    __syncthreads();
    zsh[t] = (jz < cnt) ? z[(size_t)esh[jz]*8 + hz] : 0.f;
    __syncthreads();
    #pragma unroll 8
    for (int jj = 0; jj < 32; jj++){
      int e = esh[jj];
      float efv = ldf(ef, (size_t)e*256 + t, isf32);
      float pv  = Pall[(size_t)dsh[jj]*768 + 512 + t];
      #pragma unroll
      for (int hq = 0; hq < 8; hq++) facc[hq] = fmaf(zsh[jj*8 + hq], efv, facc[hq]);
      gacc = fmaf(zsh[jj*8 + h], pv, gacc);
    }
  }
  if (t < 8){
    float ds = denom[n*8 + t];
    sinv[t] = (ds > 0.f) ? 1.f/ds : 0.f;
  }
  __syncthreads();
  #pragma unroll
  for (int hq = 0; hq < 8; hq++)
    Fs[hq*257 + t] = facc[hq] * sinv[hq];
  __syncthreads();
  float am = gacc * sinv[h] + bmsg[t];
  const float* fr = Fs + h*257;
  {
    float p0=0.f, p1=0.f, p2=0.f, p3=0.f;
    for (int k = 0; k < 256; k += 4){
      p0 = fmaf(fr[k+0], Wmsg[(size_t)(256 + k + 0)*256 + t], p0);
      p1 = fmaf(fr[k+1], Wmsg[(size_t)(256 + k + 1)*256 + t], p1);
      p2 = fmaf(fr[k+2], Wmsg[(size_t)(256 + k + 2)*256 + t], p2);
      p3 = fmaf(fr[k+3], Wmsg[(size_t)(256 + k + 3)*256 + t], p3);
    }
    am += (p0 + p1) + (p2 + p3);
  }
  aggs[t] = am;
  __syncthreads();
  float o = bg[t] + ldf(nodes, (size_t)n*256 + t, isf32);
  {
    float p0=0.f, p1=0.f, p2=0.f, p3=0.f;
    for (int k = 0; k < 256; k += 4){
      p0 = fmaf(aggs[k+0], Wg[(k+0)*256 + t], p0);
      p1 = fmaf(aggs[k+1], Wg[(k+1)*256 + t], p1);
      p2 = fmaf(aggs[k+2], Wg[(k+2)*256 + t], p2);
      p3 = fmaf(aggs[k+3], Wg[(k+3)*256 + t], p3);
    }
    o += (p0 + p1) + (p2 + p3);
  }
  nodes1[n*256 + t] = o;
  float mu, rstd;
  ln_stats(o, t, r1, r2, mu, rstd);
  float x2 = (o - mu) * rstd * g2[t] + b2v[t];
  aggs[t] = x2;
  __syncthreads();
  float q = bq[t];
  {
    float p0=0.f, p1=0.f, p2=0.f, p3=0.f;
    for (int k = 0; k < 256; k += 4){
      p0 = fmaf(aggs[k+0], Wq[(k+0)*256 + t], p0);
      p1 = fmaf(aggs[k+1], Wq[(k+1)*256 + t], p1);
      p2 = fmaf(aggs[k+2], Wq[(k+2)*256 + t], p2);
      p3 = fmaf(aggs[k+3], Wq[(k+3)*256 + t], p3);
    }
    q += (p0 + p1) + (p2 + p3);
  }
  qbuf[n*256 + t] = q;
}

// ---- cpb: float4-packed LDS (3 ds_reads/j instead of 11), 2 positions/thread ----
// positions pos0 = blk*512+t and pos1 = pos0+256 always share (b,q): pos&1023
// stays within one 1024-block. 16 independent accumulators = 2x VALU ILP.
__global__ __launch_bounds__(256) void k_cpb(
    const void* __restrict__ rel, const void* __restrict__ nodes,
    const float* __restrict__ Wc1, const float* __restrict__ bc1,
    const float* __restrict__ Wc2, const float* __restrict__ bc2, bf16* __restrict__ bias)
{
  __shared__ float4 wp[256];
  __shared__ float4 w2v[256][2];
  __shared__ float b2s[8];
  __shared__ int dsh;
  int t = threadIdx.x;
  bool isf32 = get_isf32(nodes, t, &dsh);
  wp[t] = make_float4(Wc1[t], Wc1[256 + t], bc1[t], 0.f);
  w2v[t][0] = *(const float4*)(Wc2 + t*8);
  w2v[t][1] = *(const float4*)(Wc2 + t*8 + 4);
  if (t < 8) b2s[t] = bc2[t];
  __syncthreads();
  size_t pos0 = (size_t)blockIdx.x*512 + t;
  size_t pos1 = pos0 + 256;
  float c00, c01, c10, c11;
  if (isf32){
    float2 v0 = ((const float2*)rel)[pos0]; c00 = v0.x; c01 = v0.y;
    float2 v1 = ((const float2*)rel)[pos1]; c10 = v1.x; c11 = v1.y;
  } else {
    unsigned v0 = ((const unsigned*)rel)[pos0];
    c00 = bfbits2f((unsigned short)(v0 & 0xffff));
    c01 = bfbits2f((unsigned short)(v0 >> 16));
    unsigned v1 = ((const unsigned*)rel)[pos1];
    c10 = bfbits2f((unsigned short)(v1 & 0xffff));
    c11 = bfbits2f((unsigned short)(v1 >> 16));
  }
  float a0[8] = {}, a1[8] = {};
  #pragma unroll 4
  for (int j = 0; j < 256; j++){
    float4 w  = wp[j];
    float4 wa = w2v[j][0];
    float4 wb = w2v[j][1];
    float h0 = fmaf(c00, w.x, fmaf(c01, w.y, w.z)); h0 = fmaxf(h0, 0.f);
    float h1 = fmaf(c10, w.x, fmaf(c11, w.y, w.z)); h1 = fmaxf(h1, 0.f);
    a0[0] = fmaf(h0, wa.x, a0[0]); a0[1] = fmaf(h0, wa.y, a0[1]);
    a0[2] = fmaf(h0, wa.z, a0[2]); a0[3] = fmaf(h0, wa.w, a0[3]);
    a0[4] = fmaf(h0, wb.x, a0[4]); a0[5] = fmaf(h0, wb.y, a0[5]);
    a0[6] = fmaf(h0, wb.z, a0[6]); a0[7] = fmaf(h0, wb.w, a0[7]);
    a1[0] = fmaf(h1, wa.x, a1[0]); a1[1] = fmaf(h1, wa.y, a1[1]);
    a1[2] = fmaf(h1, wa.z, a1[2]); a1[3] = fmaf(h1, wa.w, a1[3]);
    a1[4] = fmaf(h1, wb.x, a1[4]); a1[5] = fmaf(h1, wb.y, a1[5]);
    a1[6] = fmaf(h1, wb.z, a1[6]); a1[7] = fmaf(h1, wb.w, a1[7]);
  }
  size_t qq = pos0 >> 10;
  size_t b = qq / NQ_, q = qq % NQ_;
  int k0 = (int)(pos0 & 1023), k1 = k0 + 256;
  bf16* dst = bias + ((b*NH_)*NQ_ + q)*NK_;
  #pragma unroll
  for (int h = 0; h < 8; h++){
    dst[(size_t)h*NQ_*NK_ + k0] = __float2bfloat16(a0[h] + b2s[h]);
    dst[(size_t)h*NQ_*NK_ + k1] = __float2bfloat16(a1[h] + b2s[h]);
  }
}

// ---- cross attention: block per (qtile=8, h, b); writes Y bf16 scrambled ----
__global__ __launch_bounds__(256) void k_attn(
    const float* __restrict__ qbuf, const float* __restrict__ kbuf, const float* __restrict__ vT,
    const bf16* __restrict__ bias, bf16* __restrict__ Yb)
{
  __shared__ float Qs[8*33];
  __shared__ float Ks[128*33];
  __shared__ float Sc[8*1024];
  __shared__ float Op[4*8*32];
  __shared__ float qs[8];
  int qt = blockIdx.x, h = blockIdx.y, b = blockIdx.z;
  int q0 = qt*8;
  int t = threadIdx.x;
  {
    int q = t >> 5, d = t & 31;
    int gq = q0 + q;
    Qs[q*33 + d] = (gq < NQ_) ? qbuf[((size_t)b*NQ_ + gq)*256 + h*32 + d] : 0.f;
  }
  const float* kbase = kbuf + (size_t)b*NK_*256 + h*32;
  const bf16*  bb    = bias + ((size_t)(b*NH_ + h)*NQ_)*NK_;
  int kl = t & 127;
  int qb = (t >> 7) * 4;
  for (int kt = 0; kt < 8; kt++){
    int k0 = kt*128;
    __syncthreads();
    {
      int r = t >> 1, c0 = (t & 1) * 16;
      const float* src = kbase + (size_t)(k0 + r)*256 + c0;
      float* dst = Ks + r*33 + c0;
      #pragma unroll
      for (int ii = 0; ii < 4; ii++){
        float4 f = *(const float4*)(src + ii*4);
        dst[ii*4+0]=f.x; dst[ii*4+1]=f.y; dst[ii*4+2]=f.z; dst[ii*4+3]=f.w;
      }
    }
    __syncthreads();
    float a0=0.f, a1=0.f, a2=0.f, a3=0.f;
    const float* kr = Ks + kl*33;
    #pragma unroll
    for (int i = 0; i < 32; i++){
      float kd = kr[i];
      a0 = fmaf(kd, Qs[(qb+0)*33+i], a0);
      a1 = fmaf(kd, Qs[(qb+1)*33+i], a1);
      a2 = fmaf(kd, Qs[(qb+2)*33+i], a2);
      a3 = fmaf(kd, Qs[(qb+3)*33+i], a3);
    }
    float av[4] = {a0,a1,a2,a3};
    #pragma unroll
    for (int j = 0; j < 4; j++){
      int gq = min(q0 + qb + j, NQ_-1);
      float s = av[j]*0.17677669529663689f + b2f(bb[(size_t)gq*NK_ + k0 + kl]);
      Sc[(qb+j)*1024 + k0 + kl] = s;
    }
  }
  __syncthreads();
  {
    int q = t >> 5, j = t & 31;
    float m = -1e30f;
    for (int k = j; k < 1024; k += 32) m = fmaxf(m, Sc[q*1024 + k]);
    #pragma unroll
    for (int o = 16; o; o >>= 1) m = fmaxf(m, __shfl_xor(m, o));
    float ssum = 0.f;
    for (int k = j; k < 1024; k += 32){
      float e = __expf(Sc[q*1024 + k] - m);
      Sc[q*1024 + k] = e;
      ssum += e;
    }
    #pragma unroll
    for (int o = 16; o; o >>= 1) ssum += __shfl_xor(ssum, o);
    if (j == 0) qs[q] = ssum;
  }
  int d = t & 31, qg = (t >> 5) & 1, ks = t >> 6;
  const float* vrb = vT + (((size_t)(b*NH_ + h))*32)*NK_;
  float o0=0.f, o1=0.f, o2=0.f, o3=0.f;
  for (int kt = 0; kt < 8; kt++){
    int k0 = kt*128;
    __syncthreads();
    {
      int d2 = t >> 3, kq = (t & 7) * 16;
      const float* src = vrb + (size_t)d2*NK_ + k0 + kq;
      #pragma unroll
      for (int ii = 0; ii < 4; ii++){
        float4 f = *(const float4*)(src + ii*4);
        Ks[(kq+ii*4+0)*33 + d2] = f.x;
        Ks[(kq+ii*4+1)*33 + d2] = f.y;
        Ks[(kq+ii*4+2)*33 + d2] = f.z;
        Ks[(kq+ii*4+3)*33 + d2] = f.w;
      }
    }
    __syncthreads();
    const float* sc0 = Sc + (qg*4+0)*1024 + k0 + ks*32;
    const float* sc1 = Sc + (qg*4+1)*1024 + k0 + ks*32;
    const float* sc2 = Sc + (qg*4+2)*1024 + k0 + ks*32;
    const float* sc3 = Sc + (qg*4+3)*1024 + k0 + ks*32;
    #pragma unroll
    for (int kk = 0; kk < 32; kk++){
      float vv = Ks[(ks*32+kk)*33 + d];
      o0 = fmaf(sc0[kk], vv, o0);
      o1 = fmaf(sc1[kk], vv, o1);
      o2 = fmaf(sc2[kk], vv, o2);
      o3 = fmaf(sc3[kk], vv, o3);
    }
  }
  Op[((ks*8) + qg*4 + 0)*32 + d] = o0;
  Op[((ks*8) + qg*4 + 1)*32 + d] = o1;
  Op[((ks*8) + qg*4 + 2)*32 + d] = o2;
  Op[((ks*8) + qg*4 + 3)*32 + d] = o3;
  __syncthreads();
  {
    int q = t >> 5, dd = t & 31;
    int gq = q0 + q;
    if (gq < NQ_){
      float s = Op[(0*8+q)*32+dd] + Op[(1*8+q)*32+dd]
              + Op[(2*8+q)*32+dd] + Op[(3*8+q)*32+dd];
      float sv = s / qs[q];
      int tt = h*NQ_ + gq;
      Yb[((size_t)b*NQ_ + (tt >> 3))*256 + (tt & 7)*32 + dd] = __float2bfloat16(sv);
    }
  }
}

// ---- LN3: n2 -> x3 (f32 + bf16) ----
__global__ __launch_bounds__(256) void k_ln3(
    const float* __restrict__ n2, const float* __restrict__ g3, const float* __restrict__ b3,
    float* __restrict__ x3f, bf16* __restrict__ x3b)
{
  __shared__ float r1[4], r2[4];
  int n = blockIdx.x, t = threadIdx.x;
  float v = n2[n*256 + t];
  float mu, rstd;
  ln_stats(v, t, r1, r2, mu, rstd);
  float x3 = (v - mu) * rstd * g3[t] + b3[t];
  x3f[n*256 + t] = x3;
  x3b[n*256 + t] = __float2bfloat16(x3);
}

extern "C" void kernel_launch(void* const* d_in, const int* in_sizes, int n_in,
                              void* d_out, int out_size, void* d_ws, size_t ws_size,
                              hipStream_t stream)
{
  const void* nodes  = d_in[0];
  const void* images = d_in[1];
  const void* rel    = d_in[2];
  const void* ef     = d_in[3];
  const int*  ei     = (const int*)d_in[4];
  float* out = (float*)d_out;

  char* w = (char*)d_ws;
  auto alloc = [&](size_t bytes) -> void* {
    void* p = (void*)w; w += (bytes + 255) & ~(size_t)255; return p;
  };
  float*    Wall   = (float*)   alloc((size_t)WTOT*4);                 //  4.75 MB
  bf16*     Wbt    = (bf16*)    alloc((size_t)983040*2);               //  1.97 MB
  bf16*     bias   = (bf16*)    alloc((size_t)NB_*NH_*NQ_*NK_*2);      //  9.8 MB
  float*    zbuf   = (float*)   alloc((size_t)E_*8*4);                 //  4.2 MB
  float*    Pall   = (float*)   alloc((size_t)N_*768*4);               //  1.8 MB
  float*    nodes1 = (float*)   alloc(N_*256*4);
  float*    qbuf   = (float*)   alloc(N_*256*4);
  float*    kbuf   = (float*)   alloc((size_t)NB_*NK_*256*4);          //  2.1 MB
  float*    vT     = (float*)   alloc((size_t)NB_*NH_*32*NK_*4);       //  2.1 MB
  float*    n2buf  = (float*)   alloc(N_*256*4);
  float*    x3f    = (float*)   alloc(N_*256*4);
  bf16*     x1     = (bf16*)    alloc(N_*256*2);
  bf16*     x3b    = (bf16*)    alloc(N_*256*2);
  bf16*     Yb     = (bf16*)    alloc(N_*256*2);
  bf16*     H1     = (bf16*)    alloc((size_t)N_*1024*2);              //  1.2 MB
  float*    denom  = (float*)   alloc(N_*8*4);
  int*      cnt    = (int*)     alloc(N_*4);
  int*      offs   = (int*)     alloc((N_+1)*4);
  int*      cursor = (int*)     alloc(N_*4);
  int*      eorder = (int*)     alloc((size_t)E_*4);                   //  0.5 MB
  // base total ~= 32 MB; He sized adaptively from remaining workspace
  size_t used = (size_t)(w - (char*)d_ws);
  int CH = E_;
  while (CH > 2048 && used + (size_t)CH*256*2 + 256 > ws_size) CH >>= 1;
  bf16* He = (bf16*)alloc((size_t)CH*256*2);

  // Wbt sub-buffers
  bf16* WeT  = Wbt + 0;
  bf16* WkvT = Wbt + 65536;
  bf16* WnpT = Wbt + 196608;
  bf16* WcoT = Wbt + 393216;
  bf16* Wf1T = Wbt + 458752;
  bf16* Wf2T = Wbt + 720896;

  const float *ln2g=Wall+WOFF[2],  *ln2b=Wall+WOFF[3];
  const float *ln3g=Wall+WOFF[4],  *ln3b=Wall+WOFF[5];
  const float *bni=Wall+WOFF[7],  *bnj=Wall+WOFF[9], *be=Wall+WOFF[10];
  const float *ap =Wall+WOFF[11];
  const float *Wmsg=Wall+WOFF[12], *bmsg=Wall+WOFF[13];
  const float *Wg=Wall+WOFF[14], *bg=Wall+WOFF[15];
  const float *Wq=Wall+WOFF[16], *bq=Wall+WOFF[17];
  const float *bkv=Wall+WOFF[19];
  const float *Wc1=Wall+WOFF[20], *bc1=Wall+WOFF[21];
  const float *Wc2=Wall+WOFF[22], *bc2=Wall+WOFF[23];
  const float *bco=Wall+WOFF[25];
  const float *bf1v=Wall+WOFF[27];
  const float *bf2v=Wall+WOFF[29];

  SrcTab tab;
  {
    const int idx[NWSEG] = {6,7,8,9,10,11, 12,13,14,15, 17,18, 19,20, 21,22,23,24,
                            25,26, 27,28,29,30, 31,32, 33,34,35,36, 16};
    for (int i = 0; i < NWSEG; i++) tab.p[i] = d_in[idx[i]];
  }
  TrTabP trp;
  // transpose tiles read RAW source tensors (dual-dtype), no Wall dependency
  trp.p[0] = d_in[16]; trp.d[0] = {0, 256,  256, 0};            // We   -> WeT
  trp.p[1] = d_in[25]; trp.d[1] = {0, 256,  512, 65536};        // Wkv  -> WkvT
  trp.p[2] = d_in[12]; trp.d[2] = {0, 256,  256, 196608};       // Wni  -> WnpT[0:256]
  trp.p[3] = d_in[14]; trp.d[3] = {0, 256,  256, 196608+65536}; // Wnj  -> WnpT[256:512]
  trp.p[4] = d_in[19]; trp.d[4] = {0, 256,  256, 196608+131072};// Wmsg0-> WnpT[512:768]
  trp.p[5] = d_in[31]; trp.d[5] = {0, 256,  256, 393216};       // Wco  -> WcoT
  trp.p[6] = d_in[33]; trp.d[6] = {0, 256, 1024, 458752};       // Wf1  -> Wf1T
  trp.p[7] = d_in[35]; trp.d[7] = {0,1024,  256, 720896};       // Wf2  -> Wf2T

  // 1: cvt + tr + ln1 + denom/cnt zero (all independent)
  k_prep   <<<PB_TOTAL, 256, 0, stream>>>(tab, trp, Wall, Wbt, nodes, x1, denom, cnt);
  // 2-4: edge bucketing
  k_count  <<<E_/256, 256, 0, stream>>>(ei, cnt);
  k_scan   <<<1, 1024, 0, stream>>>(cnt, offs, cursor);
  k_scatter<<<E_/256, 256, 0, stream>>>(ei, cursor, eorder);
  // 5: node projections: Pall[600x768] = x1 @ [Wni|Wnj|Wmsg0]
  k_gemm<<<dim3(5,6), 256, 0, stream>>>(x1, 0, nodes, 256, N_, WnpT, 0,
                                        Pall, 768, nullptr, nullptr, nullptr);
  // 6,7: He GEMM + logits
  for (int c0 = 0; c0 < E_; c0 += CH){
    k_gemm_dual<<<dim3(CH/128, 2), 256, 0, stream>>>(ef, c0, nodes, WeT, He);
    k_logits   <<<CH/32, 256, 0, stream>>>(He, Pall, bni, bnj, be, ap, ei,
                                           zbuf, denom, c0);
  }
  // 8: fused edge aggregation + per-node matvecs + LN2 + Wq
  k_agg  <<<N_, 256, 0, stream>>>(offs, eorder, ei, zbuf, ef, Pall, denom,
                                  bmsg, Wmsg, nodes, Wg, bg, ln2g, ln2b, Wq, bq,
                                  nodes1, qbuf);
  // 9: K/V projection GEMM: images[2048x256] @ Wkv -> kbuf + vT
  k_gemm<<<dim3(16,4), 256, 0, stream>>>(images, 1, nodes, 256, NB_*NK_, WkvT, 1,
                                         kbuf, 256, bkv, nullptr, vT);
  // 10: continuous position bias (float4-packed, 2 pos/thread)
  k_cpb  <<<NB_*NQ_*NK_/512, 256, 0, stream>>>(rel, nodes, Wc1, bc1, Wc2, bc2, bias);
  // 11: attention
  dim3 agrid((NQ_ + 7)/8, NH_, NB_);
  k_attn <<<agrid, 256, 0, stream>>>(qbuf, kbuf, vT, bias, Yb);
  // 12: out-proj + residual
  k_gemm <<<dim3(5,2), 256, 0, stream>>>(Yb, 0, nodes, 256, N_, WcoT, 2,
                                         n2buf, 256, bco, nodes1, nullptr);
  // 13: LN3
  k_ln3  <<<N_, 256, 0, stream>>>(n2buf, ln3g, ln3b, x3f, x3b);
  // 14,15: FFN
  k_gemm <<<dim3(5,8), 256, 0, stream>>>(x3b, 0, nodes, 256, N_, Wf1T, 3,
                                         H1, 1024, bf1v, nullptr, nullptr);
  k_gemm <<<dim3(5,2), 256, 0, stream>>>(H1, 0, nodes, 1024, N_, Wf2T, 2,
                                         out, 256, bf2v, x3f, nullptr);
}